// Round 11
// baseline (39.187 us; speedup 1.0000x reference)
//
#include <hip/hip_runtime.h>
#include <hip/hip_bf16.h>

namespace {

constexpr int kBatch  = 524288;
constexpr int kD      = 16;
constexpr int kOffset = 38167;   // TOTAL - N_GENRES
constexpr int kNG     = 18;

// wimg byte-offset layout (pre-swizzled bf16 weight image in d_ws).
constexpr int W1B0   = 0;        // W1^T swz [64][64] bf16 (k 0..47 valid, 48..63 zero)
constexpr int W2B0   = 8192;     // W2^T swz [32][64]
constexpr int W3B0   = 12288;    // W3^T swz [16][32]
constexpr int GB0    = 13312;    // genre A-frag table [64 rows=(4c+g)][8] bf16
constexpr int WBYTES = 14336;

typedef __attribute__((ext_vector_type(8))) short short8;   // MFMA A/B frag
typedef __attribute__((ext_vector_type(4))) float f32x4;    // MFMA C/D frag

__device__ __forceinline__ unsigned short f2bf(float f) {
    return __builtin_bit_cast(unsigned short, __float2bfloat16(f));
}
__device__ __forceinline__ unsigned pk2(float a, float b) {
    return (unsigned)f2bf(a) | ((unsigned)f2bf(b) << 16);
}
__device__ __forceinline__ float bf2f(unsigned short s) {
    union { unsigned u; float f; } v; v.u = ((unsigned)s) << 16;
    return v.f;
}

// ---------------- prep: build swizzled bf16 weight image in d_ws (verified r6-r10) ----------------
__global__ void prep_weights(const float* __restrict__ emb,
                             const float* __restrict__ W1,
                             const float* __restrict__ W2,
                             const float* __restrict__ W3,
                             unsigned short* __restrict__ wimg)
{
    const int t = (int)threadIdx.x;             // 256 threads, 1 block
    for (int i = t; i < WBYTES / 2; i += 256) wimg[i] = 0;
    __syncthreads();
    for (int i = t; i < 48 * 64; i += 256) {    // W1^T, swizzled rows
        int k = i >> 6, n = i & 63;
        int byte = W1B0 + n * 128 + ((k * 2) ^ ((n & 7) << 4));
        wimg[byte >> 1] = f2bf(W1[k * 64 + n]);
    }
    for (int i = t; i < 64 * 32; i += 256) {    // W2^T
        int k = i >> 5, n = i & 31;
        int byte = W2B0 + n * 128 + ((k * 2) ^ ((n & 7) << 4));
        wimg[byte >> 1] = f2bf(W2[k * 32 + n]);
    }
    for (int i = t; i < 32 * 16; i += 256) {    // W3^T (64B rows, XOR with n&3)
        int k = i >> 4, n = i & 15;
        int byte = W3B0 + n * 64 + ((k * 2) ^ ((n & 3) << 4));
        wimg[byte >> 1] = f2bf(W3[k * 16 + n]);
    }
    for (int i = t; i < 512; i += 256) {        // genre A-frag: row 4c+g holds G[8g+j][c]
        int c = i >> 5, r = i & 31, g = r >> 3, j = r & 7;
        int kg = 8 * g + j;
        wimg[(GB0 >> 1) + (4 * c + g) * 8 + j] =
            (kg < kNG) ? f2bf(emb[(size_t)(kOffset + kg) * kD + c]) : (unsigned short)0;
    }
}

// ---------- main kernel: 256 thr, NO barrier, 16KB LDS, weights JIT from L2 ----------
__global__ __launch_bounds__(256, 4) void deepfm_fwd(
    const int*   __restrict__ x_onehot,
    const int*   __restrict__ multi_hot,
    const float* __restrict__ emb,
    const float* __restrict__ fc,
    const unsigned short* __restrict__ wimg,
    const float* __restrict__ b1,
    const float* __restrict__ b2,
    const float* __restrict__ b3,
    const float* __restrict__ W4,
    const float* __restrict__ b4,
    const float* __restrict__ bias,
    float*       __restrict__ out)
{
    __shared__ alignas(16) unsigned short s_act[4 * 4096];  // 16384 B total

    const int t    = (int)threadIdx.x;
    const int i    = (int)blockIdx.x * 256 + t;
    const int lane = t & 63;
    const int w    = t >> 6;
    const int c    = lane & 15, g = lane >> 4;
    char* __restrict__ awc = (char*)(s_act + w * 4096);
    const char* __restrict__ wb = (const char*)wimg;

    // ===== precomputed per-lane LDS byte offsets (swizzle ((row&7)<<4) folded in) =====
    const int l7 = lane & 7;
    const int sb = lane * 128;                       // own-row base
    int rA[2];
    #pragma unroll
    for (int kt = 0; kt < 2; ++kt)
        rA[kt] = c * 128 + (((4 * kt + g) ^ (c & 7)) << 4);
    int wepi[4];
    #pragma unroll
    for (int nt = 0; nt < 4; ++nt)
        wepi[nt] = c * 128 + ((((2 * nt + (g >> 1)) ^ (c & 7))) << 4) + 8 * (g & 1);

    // ---- independent global loads issued early ----
    const int2 ids = *reinterpret_cast<const int2*>(x_onehot + 2 * (size_t)i);
    int2 mh[9];
    {
        const int2* mh2 = reinterpret_cast<const int2*>(multi_hot + (size_t)kNG * i);
        #pragma unroll
        for (int q = 0; q < 9; ++q) mh[q] = mh2[q];
    }
    const short8 gfrag = *reinterpret_cast<const short8*>(wb + GB0 + (4 * c + g) * 16);

    float h[32];
    {
        const float4* eu = reinterpret_cast<const float4*>(emb + (size_t)ids.x * kD);
        #pragma unroll
        for (int q = 0; q < 4; ++q) {
            const float4 a = eu[q];
            h[4*q+0] = a.x; h[4*q+1] = a.y; h[4*q+2] = a.z; h[4*q+3] = a.w;
        }
        const float4* ei = reinterpret_cast<const float4*>(emb + (size_t)ids.y * kD);
        #pragma unroll
        for (int q = 0; q < 4; ++q) {
            const float4 a = ei[q];
            h[16+4*q+0] = a.x; h[16+4*q+1] = a.y; h[16+4*q+2] = a.z; h[16+4*q+3] = a.w;
        }
    }

    // ---- first-order term ----
    float lin = bias[0] + b4[0] + fc[ids.x] + fc[ids.y];
    #pragma unroll
    for (int q = 0; q < 9; ++q) {
        lin += mh[q].x ? fc[kOffset + 2 * q]     : 0.f;
        lin += mh[q].y ? fc[kOffset + 2 * q + 1] : 0.f;
    }

    // ---- stage m-row (bf16 0/1) into cols 32..63 (granules 4..7) ----
    {
        unsigned mw[9];
        #pragma unroll
        for (int q = 0; q < 9; ++q)
            mw[q] = (mh[q].x ? 0x3F80u : 0u) | (mh[q].y ? 0x3F800000u : 0u);
        uint4 v0; v0.x = mw[0]; v0.y = mw[1]; v0.z = mw[2]; v0.w = mw[3];
        uint4 v1; v1.x = mw[4]; v1.y = mw[5]; v1.z = mw[6]; v1.w = mw[7];
        uint4 v2; v2.x = mw[8]; v2.y = 0u;    v2.z = 0u;    v2.w = 0u;
        uint4 vz; vz.x = vz.y = vz.z = vz.w = 0u;
        *reinterpret_cast<uint4*>(awc + sb + ((4 ^ l7) << 4)) = v0;
        *reinterpret_cast<uint4*>(awc + sb + ((5 ^ l7) << 4)) = v1;
        *reinterpret_cast<uint4*>(awc + sb + ((6 ^ l7) << 4)) = v2;
        *reinterpret_cast<uint4*>(awc + sb + ((7 ^ l7) << 4)) = vz;
    }

    // ---- pack e_user|e_item -> cols 0..31 ----
    {
        #pragma unroll
        for (int q = 0; q < 4; ++q) {
            uint4 d;
            d.x = pk2(h[8*q+0], h[8*q+1]);
            d.y = pk2(h[8*q+2], h[8*q+3]);
            d.z = pk2(h[8*q+4], h[8*q+5]);
            d.w = pk2(h[8*q+6], h[8*q+7]);
            *reinterpret_cast<uint4*>(awc + sb + ((q ^ l7) << 4)) = d;
        }
    }

    // ---- FM part 1 (register-only) ----
    float fm = 0.f;
    #pragma unroll
    for (int d = 0; d < kD; ++d) fm = fmaf(h[d], h[16 + d], fm);

    const f32x4 z4 = {0.f, 0.f, 0.f, 0.f};

    // ---- embedding-bag (transposed): reads mask cols 32..63, writes e_mh cols 32..47 ----
    // Same-wave DS program order guarantees the mask writes above are visible.
    {
        short8 bm[4];
        #pragma unroll
        for (int st = 0; st < 4; ++st)
            bm[st] = *reinterpret_cast<const short8*>(awc + rA[1] + 2048 * st);
        #pragma unroll
        for (int st = 0; st < 4; ++st) {
            const f32x4 accb = __builtin_amdgcn_mfma_f32_16x16x32_bf16(gfrag, bm[st], z4, 0, 0, 0);
            uint2 dv;
            dv.x = pk2(accb[0], accb[1]);
            dv.y = pk2(accb[2], accb[3]);
            *reinterpret_cast<uint2*>(awc + wepi[2] + 2048 * st) = dv;
        }
        uint4 vz; vz.x = vz.y = vz.z = vz.w = 0u;   // L1 K-pad cols 48..63
        *reinterpret_cast<uint4*>(awc + sb + ((6 ^ l7) << 4)) = vz;
        *reinterpret_cast<uint4*>(awc + sb + ((7 ^ l7) << 4)) = vz;
    }

    // ---- issue L1 weight frags + biases (L2 latency hides under FM part 2) ----
    short8 aW1[4][2];
    #pragma unroll
    for (int nt = 0; nt < 4; ++nt)
        #pragma unroll
        for (int kt = 0; kt < 2; ++kt)
            aW1[nt][kt] = *reinterpret_cast<const short8*>(wb + W1B0 + rA[kt] + 2048 * nt);
    float4 b1q[4];
    #pragma unroll
    for (int nt = 0; nt < 4; ++nt)
        b1q[nt] = *reinterpret_cast<const float4*>(b1 + 16 * nt + 4 * g);

    // ---- FM part 2: read back own e_mh (cols 32..47) ----
    {
        const uint4 p0 = *reinterpret_cast<const uint4*>(awc + sb + ((4 ^ l7) << 4));
        const uint4 p1 = *reinterpret_cast<const uint4*>(awc + sb + ((5 ^ l7) << 4));
        const unsigned pp[8] = {p0.x, p0.y, p0.z, p0.w, p1.x, p1.y, p1.z, p1.w};
        #pragma unroll
        for (int j = 0; j < 8; ++j) {
            const float e0 = bf2f((unsigned short)(pp[j] & 0xFFFFu));
            const float e1 = bf2f((unsigned short)(pp[j] >> 16));
            fm = fmaf(h[2*j]   + h[16 + 2*j],   e0, fm);
            fm = fmaf(h[2*j+1] + h[16 + 2*j+1], e1, fm);
        }
    }

    // ================= L1 (transposed): h1^T = W1^T @ act^T, K=48 padded to 64 =========
    {
        short8 bA[4][2];
        #pragma unroll
        for (int st = 0; st < 4; ++st)
            #pragma unroll
            for (int kt = 0; kt < 2; ++kt)
                bA[st][kt] = *reinterpret_cast<const short8*>(awc + rA[kt] + 2048 * st);
        #pragma unroll
        for (int st = 0; st < 4; ++st) {
            f32x4 acc[4];
            #pragma unroll
            for (int nt = 0; nt < 4; ++nt) acc[nt] = z4;
            #pragma unroll
            for (int kt = 0; kt < 2; ++kt)
                #pragma unroll
                for (int nt = 0; nt < 4; ++nt)
                    acc[nt] = __builtin_amdgcn_mfma_f32_16x16x32_bf16(aW1[nt][kt], bA[st][kt], acc[nt], 0, 0, 0);
            #pragma unroll
            for (int nt = 0; nt < 4; ++nt) {
                const float v0 = fmaxf(acc[nt][0] + b1q[nt].x, 0.f);
                const float v1 = fmaxf(acc[nt][1] + b1q[nt].y, 0.f);
                const float v2 = fmaxf(acc[nt][2] + b1q[nt].z, 0.f);
                const float v3 = fmaxf(acc[nt][3] + b1q[nt].w, 0.f);
                uint2 dv; dv.x = pk2(v0, v1); dv.y = pk2(v2, v3);
                *reinterpret_cast<uint2*>(awc + wepi[nt] + 2048 * st) = dv;
            }
        }
    }

    // ---- issue L2/L3 weight frags + biases (hide under L2 compute) ----
    short8 aW2[2][2];
    #pragma unroll
    for (int nt = 0; nt < 2; ++nt)
        #pragma unroll
        for (int kt = 0; kt < 2; ++kt)
            aW2[nt][kt] = *reinterpret_cast<const short8*>(wb + W2B0 + rA[kt] + 2048 * nt);
    const short8 aW3 = *reinterpret_cast<const short8*>(wb + W3B0 + c * 64 + ((g ^ (c & 3)) << 4));
    float4 b2q[2];
    #pragma unroll
    for (int nt = 0; nt < 2; ++nt)
        b2q[nt] = *reinterpret_cast<const float4*>(b2 + 16 * nt + 4 * g);
    const float4 b3q = *reinterpret_cast<const float4*>(b3 + 4 * g);
    const float4 w4q = *reinterpret_cast<const float4*>(W4 + 4 * g);

    // ================= L2 (transposed): h2^T = W2^T @ h1^T =================
    {
        short8 bA[4][2];
        #pragma unroll
        for (int st = 0; st < 4; ++st)
            #pragma unroll
            for (int kt = 0; kt < 2; ++kt)
                bA[st][kt] = *reinterpret_cast<const short8*>(awc + rA[kt] + 2048 * st);
        #pragma unroll
        for (int st = 0; st < 4; ++st) {
            f32x4 acc[2];
            #pragma unroll
            for (int nt = 0; nt < 2; ++nt) acc[nt] = z4;
            #pragma unroll
            for (int kt = 0; kt < 2; ++kt)
                #pragma unroll
                for (int nt = 0; nt < 2; ++nt)
                    acc[nt] = __builtin_amdgcn_mfma_f32_16x16x32_bf16(aW2[nt][kt], bA[st][kt], acc[nt], 0, 0, 0);
            #pragma unroll
            for (int nt = 0; nt < 2; ++nt) {
                const float v0 = fmaxf(acc[nt][0] + b2q[nt].x, 0.f);
                const float v1 = fmaxf(acc[nt][1] + b2q[nt].y, 0.f);
                const float v2 = fmaxf(acc[nt][2] + b2q[nt].z, 0.f);
                const float v3 = fmaxf(acc[nt][3] + b2q[nt].w, 0.f);
                uint2 dv; dv.x = pk2(v0, v1); dv.y = pk2(v2, v3);
                *reinterpret_cast<uint2*>(awc + wepi[nt] + 2048 * st) = dv;
            }
        }
    }

    // ================= L3 + L4 fully in registers =================
    float tot[4];
    {
        short8 bA[4];
        #pragma unroll
        for (int st = 0; st < 4; ++st)
            bA[st] = *reinterpret_cast<const short8*>(awc + rA[0] + 2048 * st);
        #pragma unroll
        for (int st = 0; st < 4; ++st) {
            const f32x4 a3 = __builtin_amdgcn_mfma_f32_16x16x32_bf16(aW3, bA[st], z4, 0, 0, 0);
            float p = 0.f;
            p = fmaf(fmaxf(a3[0] + b3q.x, 0.f), w4q.x, p);
            p = fmaf(fmaxf(a3[1] + b3q.y, 0.f), w4q.y, p);
            p = fmaf(fmaxf(a3[2] + b3q.z, 0.f), w4q.z, p);
            p = fmaf(fmaxf(a3[3] + b3q.w, 0.f), w4q.w, p);
            p += __shfl_xor(p, 16, 64);
            p += __shfl_xor(p, 32, 64);
            tot[st] = p;
        }
    }
    const float m01 = (g & 1) ? tot[1] : tot[0];
    const float m23 = (g & 1) ? tot[3] : tot[2];
    const float mlp = (g & 2) ? m23 : m01;

    const float x = lin + fm + mlp;
    out[i] = 1.0f / (1.0f + __expf(-x));
}

} // namespace

extern "C" void kernel_launch(void* const* d_in, const int* in_sizes, int n_in,
                              void* d_out, int out_size, void* d_ws, size_t ws_size,
                              hipStream_t stream) {
    (void)in_sizes; (void)n_in; (void)ws_size; (void)out_size;
    const int*   x_onehot  = (const int*)  d_in[0];
    const int*   multi_hot = (const int*)  d_in[1];
    const float* emb       = (const float*)d_in[2];
    const float* fc        = (const float*)d_in[3];
    const float* W1        = (const float*)d_in[4];
    const float* b1        = (const float*)d_in[5];
    const float* W2        = (const float*)d_in[6];
    const float* b2        = (const float*)d_in[7];
    const float* W3        = (const float*)d_in[8];
    const float* b3        = (const float*)d_in[9];
    const float* W4        = (const float*)d_in[10];
    const float* b4        = (const float*)d_in[11];
    const float* biasp     = (const float*)d_in[12];
    float* out = (float*)d_out;
    unsigned short* wimg = (unsigned short*)d_ws;

    hipLaunchKernelGGL(prep_weights, dim3(1), dim3(256), 0, stream,
                       emb, W1, W2, W3, wimg);
    hipLaunchKernelGGL(deepfm_fwd, dim3(kBatch / 256), dim3(256), 0, stream,
                       x_onehot, multi_hot, emb, fc, wimg,
                       b1, b2, b3, W4, b4, biasp, out);
}

// Round 12
// 37.793 us; speedup vs baseline: 1.0369x; 1.0369x over previous
//
#include <hip/hip_runtime.h>
#include <hip/hip_bf16.h>

namespace {

constexpr int kBatch  = 524288;
constexpr int kD      = 16;
constexpr int kOffset = 38167;   // TOTAL - N_GENRES
constexpr int kNG     = 18;

// wimg byte-offset layout (pre-swizzled bf16 weight image in d_ws).
constexpr int W1B0   = 0;        // W1^T swz [64][64] bf16 (k 0..47 valid, 48..63 zero)
constexpr int W2B0   = 8192;     // W2^T swz [32][64]
constexpr int W3B0   = 12288;    // W3^T swz [16][32]
constexpr int GB0    = 13312;    // genre A-frag table [64 rows=(4c+g)][8] bf16
constexpr int WBYTES = 14336;

typedef __attribute__((ext_vector_type(8))) short short8;   // MFMA A/B frag
typedef __attribute__((ext_vector_type(4))) float f32x4;    // MFMA C/D frag
typedef __attribute__((ext_vector_type(2))) float f32x2;

__device__ __forceinline__ unsigned short f2bf(float f) {
    return __builtin_bit_cast(unsigned short, __float2bfloat16(f));
}
__device__ __forceinline__ unsigned pk2(float a, float b) {
    return (unsigned)f2bf(a) | ((unsigned)f2bf(b) << 16);
}
__device__ __forceinline__ float bf2f(unsigned short s) {
    union { unsigned u; float f; } v; v.u = ((unsigned)s) << 16;
    return v.f;
}

// ------------- prep: swizzled bf16 weight image in d_ws; now 16 blocks -------------
__global__ void prep_weights(const float* __restrict__ emb,
                             const float* __restrict__ W1,
                             const float* __restrict__ W2,
                             const float* __restrict__ W3,
                             unsigned short* __restrict__ wimg)
{
    const int t0 = (int)blockIdx.x * 256 + (int)threadIdx.x;   // 16*256 = 4096 threads
    const int STRIDE = 4096;
    // image is mostly overwritten below; zero only the pad regions explicitly:
    // W1 cols 48..63 region (k-pad) and unreferenced gaps are covered by the stores
    // below plus this zero pass over the whole image (cheap, fully parallel).
    for (int i = t0; i < WBYTES / 2; i += STRIDE) wimg[i] = 0;
    // NOTE: cross-block visibility of the zeros vs. the scatter stores below is not
    // ordered; make each block zero exactly the slice it later writes is NOT possible
    // for overlapping regions, so instead: the scatter stores below never depend on
    // the zeros (they overwrite), and the zero-only locations (pads) are touched by
    // no scatter store. Both passes use the same grid-stride partition of DISJOINT
    // index spaces, so no cross-block ordering is required except pad-vs-store
    // disjointness, which holds by construction.
    for (int i = t0; i < 48 * 64; i += STRIDE) {    // W1^T, swizzled rows
        int k = i >> 6, n = i & 63;
        int byte = W1B0 + n * 128 + ((k * 2) ^ ((n & 7) << 4));
        wimg[byte >> 1] = f2bf(W1[k * 64 + n]);
    }
    for (int i = t0; i < 64 * 32; i += STRIDE) {    // W2^T
        int k = i >> 5, n = i & 31;
        int byte = W2B0 + n * 128 + ((k * 2) ^ ((n & 7) << 4));
        wimg[byte >> 1] = f2bf(W2[k * 32 + n]);
    }
    for (int i = t0; i < 32 * 16; i += STRIDE) {    // W3^T (64B rows, XOR with n&3)
        int k = i >> 4, n = i & 15;
        int byte = W3B0 + n * 64 + ((k * 2) ^ ((n & 3) << 4));
        wimg[byte >> 1] = f2bf(W3[k * 16 + n]);
    }
    for (int i = t0; i < 512; i += STRIDE) {        // genre A-frag: row 4c+g holds G[8g+j][c]
        int c = i >> 5, r = i & 31, g = r >> 3, j = r & 7;
        int kg = 8 * g + j;
        wimg[(GB0 >> 1) + (4 * c + g) * 8 + j] =
            (kg < kNG) ? f2bf(emb[(size_t)(kOffset + kg) * kD + c]) : (unsigned short)0;
    }
}

// ---------- main kernel: 256 thr, NO barrier, 16KB LDS, weights JIT from L2 ----------
__global__ __launch_bounds__(256, 4) void deepfm_fwd(
    const int*   __restrict__ x_onehot,
    const int*   __restrict__ multi_hot,
    const float* __restrict__ emb,
    const float* __restrict__ fc,
    const unsigned short* __restrict__ wimg,
    const float* __restrict__ b1,
    const float* __restrict__ b2,
    const float* __restrict__ b3,
    const float* __restrict__ W4,
    const float* __restrict__ b4,
    const float* __restrict__ bias,
    float*       __restrict__ out)
{
    __shared__ alignas(16) unsigned short s_act[4 * 4096];  // 16384 B total

    const int t    = (int)threadIdx.x;
    const int i    = (int)blockIdx.x * 256 + t;
    const int lane = t & 63;
    const int w    = t >> 6;
    const int c    = lane & 15, g = lane >> 4;
    char* __restrict__ awc = (char*)(s_act + w * 4096);
    const char* __restrict__ wb = (const char*)wimg;

    // ===== precomputed per-lane LDS byte offsets (swizzle ((row&7)<<4) folded in) =====
    const int l7 = lane & 7;
    const int sb = lane * 128;                       // own-row base
    int rA[2];
    #pragma unroll
    for (int kt = 0; kt < 2; ++kt)
        rA[kt] = c * 128 + (((4 * kt + g) ^ (c & 7)) << 4);
    int wepi[4];
    #pragma unroll
    for (int nt = 0; nt < 4; ++nt)
        wepi[nt] = c * 128 + ((((2 * nt + (g >> 1)) ^ (c & 7))) << 4) + 8 * (g & 1);

    // ---- independent global loads issued early ----
    const int2 ids = *reinterpret_cast<const int2*>(x_onehot + 2 * (size_t)i);
    int2 mh[9];
    {
        const int2* mh2 = reinterpret_cast<const int2*>(multi_hot + (size_t)kNG * i);
        #pragma unroll
        for (int q = 0; q < 9; ++q) mh[q] = mh2[q];
    }
    const short8 gfrag = *reinterpret_cast<const short8*>(wb + GB0 + (4 * c + g) * 16);

    float h[32];
    {
        const float4* eu = reinterpret_cast<const float4*>(emb + (size_t)ids.x * kD);
        #pragma unroll
        for (int q = 0; q < 4; ++q) {
            const float4 a = eu[q];
            h[4*q+0] = a.x; h[4*q+1] = a.y; h[4*q+2] = a.z; h[4*q+3] = a.w;
        }
        const float4* ei = reinterpret_cast<const float4*>(emb + (size_t)ids.y * kD);
        #pragma unroll
        for (int q = 0; q < 4; ++q) {
            const float4 a = ei[q];
            h[16+4*q+0] = a.x; h[16+4*q+1] = a.y; h[16+4*q+2] = a.z; h[16+4*q+3] = a.w;
        }
    }

    // ---- first-order term ----
    float lin = bias[0] + b4[0] + fc[ids.x] + fc[ids.y];
    #pragma unroll
    for (int q = 0; q < 9; ++q) {
        lin += mh[q].x ? fc[kOffset + 2 * q]     : 0.f;
        lin += mh[q].y ? fc[kOffset + 2 * q + 1] : 0.f;
    }

    // ---- stage m-row (bf16 0/1) into cols 32..63 (granules 4..7) ----
    {
        unsigned mw[9];
        #pragma unroll
        for (int q = 0; q < 9; ++q)
            mw[q] = (mh[q].x ? 0x3F80u : 0u) | (mh[q].y ? 0x3F800000u : 0u);
        uint4 v0; v0.x = mw[0]; v0.y = mw[1]; v0.z = mw[2]; v0.w = mw[3];
        uint4 v1; v1.x = mw[4]; v1.y = mw[5]; v1.z = mw[6]; v1.w = mw[7];
        uint4 v2; v2.x = mw[8]; v2.y = 0u;    v2.z = 0u;    v2.w = 0u;
        uint4 vz; vz.x = vz.y = vz.z = vz.w = 0u;
        *reinterpret_cast<uint4*>(awc + sb + ((4 ^ l7) << 4)) = v0;
        *reinterpret_cast<uint4*>(awc + sb + ((5 ^ l7) << 4)) = v1;
        *reinterpret_cast<uint4*>(awc + sb + ((6 ^ l7) << 4)) = v2;
        *reinterpret_cast<uint4*>(awc + sb + ((7 ^ l7) << 4)) = vz;
    }

    // ---- pack e_user|e_item -> cols 0..31 ----
    {
        #pragma unroll
        for (int q = 0; q < 4; ++q) {
            uint4 d;
            d.x = pk2(h[8*q+0], h[8*q+1]);
            d.y = pk2(h[8*q+2], h[8*q+3]);
            d.z = pk2(h[8*q+4], h[8*q+5]);
            d.w = pk2(h[8*q+6], h[8*q+7]);
            *reinterpret_cast<uint4*>(awc + sb + ((q ^ l7) << 4)) = d;
        }
    }

    // ---- FM part 1 (register-only) ----
    float fm = 0.f;
    #pragma unroll
    for (int d = 0; d < kD; ++d) fm = fmaf(h[d], h[16 + d], fm);

    const f32x4 z4 = {0.f, 0.f, 0.f, 0.f};
    const f32x2 zz = {0.f, 0.f};

    // ---- embedding-bag (transposed): reads mask cols 32..63, writes e_mh cols 32..47 ----
    {
        short8 bm[4];
        #pragma unroll
        for (int st = 0; st < 4; ++st)
            bm[st] = *reinterpret_cast<const short8*>(awc + rA[1] + 2048 * st);
        __builtin_amdgcn_s_setprio(1);
        f32x4 accb[4];
        #pragma unroll
        for (int st = 0; st < 4; ++st)
            accb[st] = __builtin_amdgcn_mfma_f32_16x16x32_bf16(gfrag, bm[st], z4, 0, 0, 0);
        __builtin_amdgcn_s_setprio(0);
        #pragma unroll
        for (int st = 0; st < 4; ++st) {
            uint2 dv;
            dv.x = pk2(accb[st][0], accb[st][1]);
            dv.y = pk2(accb[st][2], accb[st][3]);
            *reinterpret_cast<uint2*>(awc + wepi[2] + 2048 * st) = dv;
        }
        uint4 vz; vz.x = vz.y = vz.z = vz.w = 0u;   // L1 K-pad cols 48..63
        *reinterpret_cast<uint4*>(awc + sb + ((6 ^ l7) << 4)) = vz;
        *reinterpret_cast<uint4*>(awc + sb + ((7 ^ l7) << 4)) = vz;
    }

    // ---- issue L1 weight frags + biases (L2 latency hides under FM part 2) ----
    short8 aW1[4][2];
    #pragma unroll
    for (int nt = 0; nt < 4; ++nt)
        #pragma unroll
        for (int kt = 0; kt < 2; ++kt)
            aW1[nt][kt] = *reinterpret_cast<const short8*>(wb + W1B0 + rA[kt] + 2048 * nt);
    float4 b1q[4];
    #pragma unroll
    for (int nt = 0; nt < 4; ++nt)
        b1q[nt] = *reinterpret_cast<const float4*>(b1 + 16 * nt + 4 * g);

    // ---- FM part 2: read back own e_mh (cols 32..47) ----
    {
        const uint4 p0 = *reinterpret_cast<const uint4*>(awc + sb + ((4 ^ l7) << 4));
        const uint4 p1 = *reinterpret_cast<const uint4*>(awc + sb + ((5 ^ l7) << 4));
        const unsigned pp[8] = {p0.x, p0.y, p0.z, p0.w, p1.x, p1.y, p1.z, p1.w};
        #pragma unroll
        for (int j = 0; j < 8; ++j) {
            const float e0 = bf2f((unsigned short)(pp[j] & 0xFFFFu));
            const float e1 = bf2f((unsigned short)(pp[j] >> 16));
            fm = fmaf(h[2*j]   + h[16 + 2*j],   e0, fm);
            fm = fmaf(h[2*j+1] + h[16 + 2*j+1], e1, fm);
        }
    }

    // ================= L1 (transposed): h1^T = W1^T @ act^T, K=48 padded to 64 =========
    {
        short8 bA[4][2];
        #pragma unroll
        for (int st = 0; st < 4; ++st)
            #pragma unroll
            for (int kt = 0; kt < 2; ++kt)
                bA[st][kt] = *reinterpret_cast<const short8*>(awc + rA[kt] + 2048 * st);
        #pragma unroll
        for (int st = 0; st < 4; ++st) {
            f32x4 acc[4];
            #pragma unroll
            for (int nt = 0; nt < 4; ++nt) acc[nt] = z4;
            __builtin_amdgcn_s_setprio(1);
            #pragma unroll
            for (int kt = 0; kt < 2; ++kt)
                #pragma unroll
                for (int nt = 0; nt < 4; ++nt)
                    acc[nt] = __builtin_amdgcn_mfma_f32_16x16x32_bf16(aW1[nt][kt], bA[st][kt], acc[nt], 0, 0, 0);
            __builtin_amdgcn_s_setprio(0);
            #pragma unroll
            for (int nt = 0; nt < 4; ++nt) {
                f32x2 p0 = {acc[nt][0], acc[nt][1]};
                f32x2 p1 = {acc[nt][2], acc[nt][3]};
                const f32x2 ba = {b1q[nt].x, b1q[nt].y};
                const f32x2 bb = {b1q[nt].z, b1q[nt].w};
                p0 += ba; p1 += bb;
                p0 = __builtin_elementwise_max(p0, zz);
                p1 = __builtin_elementwise_max(p1, zz);
                uint2 dv; dv.x = pk2(p0[0], p0[1]); dv.y = pk2(p1[0], p1[1]);
                *reinterpret_cast<uint2*>(awc + wepi[nt] + 2048 * st) = dv;
            }
        }
    }

    // ---- issue L2/L3 weight frags + biases (hide under L2 compute) ----
    short8 aW2[2][2];
    #pragma unroll
    for (int nt = 0; nt < 2; ++nt)
        #pragma unroll
        for (int kt = 0; kt < 2; ++kt)
            aW2[nt][kt] = *reinterpret_cast<const short8*>(wb + W2B0 + rA[kt] + 2048 * nt);
    const short8 aW3 = *reinterpret_cast<const short8*>(wb + W3B0 + c * 64 + ((g ^ (c & 3)) << 4));
    float4 b2q[2];
    #pragma unroll
    for (int nt = 0; nt < 2; ++nt)
        b2q[nt] = *reinterpret_cast<const float4*>(b2 + 16 * nt + 4 * g);
    const float4 b3q = *reinterpret_cast<const float4*>(b3 + 4 * g);
    const float4 w4q = *reinterpret_cast<const float4*>(W4 + 4 * g);

    // ================= L2 (transposed): h2^T = W2^T @ h1^T =================
    {
        short8 bA[4][2];
        #pragma unroll
        for (int st = 0; st < 4; ++st)
            #pragma unroll
            for (int kt = 0; kt < 2; ++kt)
                bA[st][kt] = *reinterpret_cast<const short8*>(awc + rA[kt] + 2048 * st);
        #pragma unroll
        for (int st = 0; st < 4; ++st) {
            f32x4 acc[2];
            #pragma unroll
            for (int nt = 0; nt < 2; ++nt) acc[nt] = z4;
            __builtin_amdgcn_s_setprio(1);
            #pragma unroll
            for (int kt = 0; kt < 2; ++kt)
                #pragma unroll
                for (int nt = 0; nt < 2; ++nt)
                    acc[nt] = __builtin_amdgcn_mfma_f32_16x16x32_bf16(aW2[nt][kt], bA[st][kt], acc[nt], 0, 0, 0);
            __builtin_amdgcn_s_setprio(0);
            #pragma unroll
            for (int nt = 0; nt < 2; ++nt) {
                f32x2 p0 = {acc[nt][0], acc[nt][1]};
                f32x2 p1 = {acc[nt][2], acc[nt][3]};
                const f32x2 ba = {b2q[nt].x, b2q[nt].y};
                const f32x2 bb = {b2q[nt].z, b2q[nt].w};
                p0 += ba; p1 += bb;
                p0 = __builtin_elementwise_max(p0, zz);
                p1 = __builtin_elementwise_max(p1, zz);
                uint2 dv; dv.x = pk2(p0[0], p0[1]); dv.y = pk2(p1[0], p1[1]);
                *reinterpret_cast<uint2*>(awc + wepi[nt] + 2048 * st) = dv;
            }
        }
    }

    // ================= L3 + L4 fully in registers =================
    float tot[4];
    {
        short8 bA[4];
        #pragma unroll
        for (int st = 0; st < 4; ++st)
            bA[st] = *reinterpret_cast<const short8*>(awc + rA[0] + 2048 * st);
        #pragma unroll
        for (int st = 0; st < 4; ++st) {
            __builtin_amdgcn_s_setprio(1);
            const f32x4 a3 = __builtin_amdgcn_mfma_f32_16x16x32_bf16(aW3, bA[st], z4, 0, 0, 0);
            __builtin_amdgcn_s_setprio(0);
            float p = 0.f;
            p = fmaf(fmaxf(a3[0] + b3q.x, 0.f), w4q.x, p);
            p = fmaf(fmaxf(a3[1] + b3q.y, 0.f), w4q.y, p);
            p = fmaf(fmaxf(a3[2] + b3q.z, 0.f), w4q.z, p);
            p = fmaf(fmaxf(a3[3] + b3q.w, 0.f), w4q.w, p);
            p += __shfl_xor(p, 16, 64);
            p += __shfl_xor(p, 32, 64);
            tot[st] = p;
        }
    }
    const float m01 = (g & 1) ? tot[1] : tot[0];
    const float m23 = (g & 1) ? tot[3] : tot[2];
    const float mlp = (g & 2) ? m23 : m01;

    const float x = lin + fm + mlp;
    out[i] = 1.0f / (1.0f + __expf(-x));
}

} // namespace

extern "C" void kernel_launch(void* const* d_in, const int* in_sizes, int n_in,
                              void* d_out, int out_size, void* d_ws, size_t ws_size,
                              hipStream_t stream) {
    (void)in_sizes; (void)n_in; (void)ws_size; (void)out_size;
    const int*   x_onehot  = (const int*)  d_in[0];
    const int*   multi_hot = (const int*)  d_in[1];
    const float* emb       = (const float*)d_in[2];
    const float* fc        = (const float*)d_in[3];
    const float* W1        = (const float*)d_in[4];
    const float* b1        = (const float*)d_in[5];
    const float* W2        = (const float*)d_in[6];
    const float* b2        = (const float*)d_in[7];
    const float* W3        = (const float*)d_in[8];
    const float* b3        = (const float*)d_in[9];
    const float* W4        = (const float*)d_in[10];
    const float* b4        = (const float*)d_in[11];
    const float* biasp     = (const float*)d_in[12];
    float* out = (float*)d_out;
    unsigned short* wimg = (unsigned short*)d_ws;

    hipLaunchKernelGGL(prep_weights, dim3(16), dim3(256), 0, stream,
                       emb, W1, W2, W3, wimg);
    hipLaunchKernelGGL(deepfm_fwd, dim3(kBatch / 256), dim3(256), 0, stream,
                       x_onehot, multi_hot, emb, fc, wimg,
                       b1, b2, b3, W4, b4, biasp, out);
}